// Round 7
// baseline (139.925 us; speedup 1.0000x reference)
//
#include <hip/hip_runtime.h>
#include <hip/hip_bf16.h>

#define N_SRC_N  100000
#define N_DST_N  50000
#define NE       1000000
#define IN_F     256
#define NH       4
#define ND       32
#define HD       128   // NH*ND
#define NEG_SLOPE 0.2f

#define DPB      32          // dsts per bucket
#define NB       1563        // ceil(50000/32)
#define CAP      1024        // LDS edge cap per bucket (mean 640, sd 25 -> +15 sigma)

typedef __attribute__((ext_vector_type(8))) short short8v;
typedef __attribute__((ext_vector_type(4))) short short4v;
typedef __attribute__((ext_vector_type(4))) float f32x4;

__device__ __forceinline__ short f2bf(float f) {
    __hip_bfloat16 h = __float2bfloat16(f);
    return *reinterpret_cast<short*>(&h);
}
__device__ __forceinline__ float bflo(unsigned u) { return __uint_as_float(u << 16); }
__device__ __forceinline__ float bfhi(unsigned u) { return __uint_as_float(u & 0xffff0000u); }

__device__ __forceinline__ void gl_lds16(const float* g, float* l) {
    __builtin_amdgcn_global_load_lds((const __attribute__((address_space(1))) unsigned*)g,
                                     (__attribute__((address_space(3))) unsigned*)l,
                                     16, 0, 0);
}

// ---------------- convert fc_w fp32 -> bf16 -----------------------------------------
__global__ __launch_bounds__(256) void cvt_w(const float* __restrict__ w,
                                             short* __restrict__ wb)
{
    int i4 = blockIdx.x * 256 + threadIdx.x;
    if (i4 < (HD * IN_F) / 4) {
        f32x4 v = ((const f32x4*)w)[i4];
        short4v s;
        s[0] = f2bf(v[0]); s[1] = f2bf(v[1]); s[2] = f2bf(v[2]); s[3] = f2bf(v[3]);
        ((short4v*)wb)[i4] = s;
    }
}

// ---------------- MFMA GEMM: hb = bf16(x @ w^T), el fused ---------------------------
// Full prefetch: all 4 k-tiles staged to 4 LDS buffers at block start (no reuse),
// counted vmcnt per tile (12/8/4/0) so later stages stay in flight across barriers.
// B-preload issued first (oldest 16 vmem ops) -> vmcnt(12) at tile0 also covers B.
__global__ __launch_bounds__(256) void gemm_fc_mfma(
    const float* __restrict__ x, const short* __restrict__ wb,
    const float* __restrict__ al, short* __restrict__ hb,
    float* __restrict__ el, int nrows)
{
    __shared__ float lds[4][64 * 64];     // 4 x 16KB, one buffer per k-tile

    const int w  = threadIdx.x >> 6;
    const int l  = threadIdx.x & 63;
    const int lr = l & 15;
    const int lk = l >> 4;
    const int row0 = blockIdx.x * 64;

    // B preload FIRST: 16 vmem instrs per wave (cannot sink past the volatile
    // memory-clobber waitcnt asms below)
    short8v bfr[2][8];
#pragma unroll
    for (int ct = 0; ct < 2; ++ct)
#pragma unroll
        for (int k = 0; k < 8; ++k)
            bfr[ct][k] = *(const short8v*)(wb + (size_t)(w * 32 + ct * 16 + lr) * IN_F
                                              + lk * 8 + k * 32);

    // stage all 4 k-tiles: 4 gl_lds instrs per wave per tile
#pragma unroll
    for (int t = 0; t < 4; ++t) {
#pragma unroll
        for (int i = 0; i < 4; ++i) {
            int chunk = i * 4 + w;
            int row   = chunk * 4 + (l >> 4);
            int srow  = row0 + row; if (srow > nrows - 1) srow = nrows - 1;
            int c_pos = (l & 15) * 16;
            int c_src = c_pos ^ ((row & 7) << 5);
            const float* g = x + (size_t)srow * IN_F + t * 64 + (c_src >> 2);
            gl_lds16(g, &lds[t][chunk * 256]);
        }
    }

    f32x4 acc[4][2];
#pragma unroll
    for (int rt = 0; rt < 4; ++rt)
#pragma unroll
        for (int ct = 0; ct < 2; ++ct) acc[rt][ct] = (f32x4){0.f, 0.f, 0.f, 0.f};

#define GEMM_TILE(T, N)                                                           \
    asm volatile("s_waitcnt vmcnt(" #N ")" ::: "memory");                         \
    __builtin_amdgcn_s_barrier();                                                 \
    __builtin_amdgcn_sched_barrier(0);                                            \
    _Pragma("unroll")                                                             \
    for (int kc = 0; kc < 2; ++kc) {                                              \
        _Pragma("unroll")                                                         \
        for (int rt = 0; rt < 4; ++rt) {                                          \
            int row = rt * 16 + lr;                                               \
            int cb  = (kc * 128 + lk * 32) ^ ((row & 7) << 5);                    \
            const float* p = &lds[T][0] + row * 64 + (cb >> 2);                   \
            f32x4 u0 = *(const f32x4*)p;                                          \
            f32x4 u1 = *(const f32x4*)(p + 4);                                    \
            short8v af;                                                           \
            af[0] = f2bf(u0[0]); af[1] = f2bf(u0[1]);                             \
            af[2] = f2bf(u0[2]); af[3] = f2bf(u0[3]);                             \
            af[4] = f2bf(u1[0]); af[5] = f2bf(u1[1]);                             \
            af[6] = f2bf(u1[2]); af[7] = f2bf(u1[3]);                             \
            acc[rt][0] = __builtin_amdgcn_mfma_f32_16x16x32_bf16(                 \
                             af, bfr[0][(T) * 2 + kc], acc[rt][0], 0, 0, 0);      \
            acc[rt][1] = __builtin_amdgcn_mfma_f32_16x16x32_bf16(                 \
                             af, bfr[1][(T) * 2 + kc], acc[rt][1], 0, 0, 0);      \
        }                                                                         \
    }

    GEMM_TILE(0, 12)
    GEMM_TILE(1, 8)
    GEMM_TILE(2, 4)
    GEMM_TILE(3, 0)
#undef GEMM_TILE

#pragma unroll
    for (int rt = 0; rt < 4; ++rt)
#pragma unroll
        for (int r = 0; r < 4; ++r) {
            int row = row0 + rt * 16 + lk * 4 + r;
            if (row < nrows) {
                short* hp = hb + (size_t)row * HD + w * 32 + lr;
                hp[0]  = f2bf(acc[rt][0][r]);
                hp[16] = f2bf(acc[rt][1][r]);
            }
        }

    float al0 = al[w * 32 + lr], al1 = al[w * 32 + 16 + lr];
#pragma unroll
    for (int rt = 0; rt < 4; ++rt) {
        float p[4];
#pragma unroll
        for (int r = 0; r < 4; ++r)
            p[r] = acc[rt][0][r] * al0 + acc[rt][1][r] * al1;
#pragma unroll
        for (int o = 1; o < 16; o <<= 1) {
#pragma unroll
            for (int r = 0; r < 4; ++r) p[r] += __shfl_xor(p[r], o, 64);
        }
        if (lr == 0) {
#pragma unroll
            for (int r = 0; r < 4; ++r) {
                int row = row0 + rt * 16 + lk * 4 + r;
                if (row < nrows) el[row * NH + w] = p[r];
            }
        }
    }
}

// ---------------- er[i,head] = <hb[dnid[i]], ar> per head; wave per i ---------------
__global__ __launch_bounds__(256) void er_kernel(
    const short* __restrict__ hb, const float* __restrict__ ar,
    const int* __restrict__ dnid, float* __restrict__ er, int ndst)
{
    int i = blockIdx.x * 4 + (threadIdx.x >> 6);
    if (i >= ndst) return;
    int l = threadIdx.x & 63;
    int n = dnid[i];
    unsigned u = *(const unsigned*)(hb + (size_t)n * HD + 2 * l);
    float s = bflo(u) * ar[2 * l] + bfhi(u) * ar[2 * l + 1];
#pragma unroll
    for (int o = 1; o < 16; o <<= 1) s += __shfl_xor(s, o, 64);
    if ((l & 15) == 0) er[i * NH + (l >> 4)] = s;
}

// -------- bucket histogram over dst>>5 ----------------------------------------------
__global__ __launch_bounds__(256) void bucket_hist(
    const int4* __restrict__ dst4, int* __restrict__ bcnt, int n4)
{
    __shared__ int lh[NB];
    for (int i = threadIdx.x; i < NB; i += 256) lh[i] = 0;
    __syncthreads();
#pragma unroll
    for (int q = 0; q < 4; ++q) {
        int e4 = blockIdx.x * 1024 + q * 256 + threadIdx.x;
        if (e4 < n4) {
            int4 v = dst4[e4];
            atomicAdd(&lh[v.x >> 5], 1); atomicAdd(&lh[v.y >> 5], 1);
            atomicAdd(&lh[v.z >> 5], 1); atomicAdd(&lh[v.w >> 5], 1);
        }
    }
    __syncthreads();
    for (int i = threadIdx.x; i < NB; i += 256) {
        int c = lh[i];
        if (c > 0) atomicAdd(&bcnt[i], c);
    }
}

// -------- exclusive scan of bcnt[NB] ------------------------------------------------
__global__ __launch_bounds__(1024) void bucket_scan(
    const int* __restrict__ bcnt, int* __restrict__ boff, int* __restrict__ bcur, int n)
{
    int tid = threadIdx.x;
    int i0 = 2 * tid, i1 = 2 * tid + 1;
    int a = (i0 < n) ? bcnt[i0] : 0;
    int c = (i1 < n) ? bcnt[i1] : 0;
    int s = a + c, v = s;
#pragma unroll
    for (int o = 1; o < 64; o <<= 1) {
        int t = __shfl_up(v, o, 64);
        if ((tid & 63) >= o) v += t;
    }
    __shared__ int ws[16];
    if ((tid & 63) == 63) ws[tid >> 6] = v;
    __syncthreads();
    int add = 0;
    for (int q = 0; q < (tid >> 6); ++q) add += ws[q];
    int excl = v - s + add;
    if (i0 < n) { boff[i0] = excl;     bcur[i0] = excl; }
    if (i1 < n) { boff[i1] = excl + a; bcur[i1] = excl + a; }
}

// -------- partition edges into bucket-segmented ebuf (packed src | dstlocal<<17) ----
__global__ __launch_bounds__(256) void partition(
    const int4* __restrict__ src4, const int4* __restrict__ dst4,
    int* __restrict__ bcur, int* __restrict__ ebuf, int n4)
{
    __shared__ int lh[NB];
    __shared__ int base[NB];
    for (int i = threadIdx.x; i < NB; i += 256) lh[i] = 0;
    __syncthreads();
    int4 sv[4], dv[4];
#pragma unroll
    for (int q = 0; q < 4; ++q) {
        int e4 = blockIdx.x * 1024 + q * 256 + threadIdx.x;
        if (e4 < n4) {
            sv[q] = src4[e4]; dv[q] = dst4[e4];
            atomicAdd(&lh[dv[q].x >> 5], 1); atomicAdd(&lh[dv[q].y >> 5], 1);
            atomicAdd(&lh[dv[q].z >> 5], 1); atomicAdd(&lh[dv[q].w >> 5], 1);
        } else {
            dv[q].x = -1;
        }
    }
    __syncthreads();
    for (int i = threadIdx.x; i < NB; i += 256) {
        int cnt = lh[i];
        base[i] = (cnt > 0) ? atomicAdd(&bcur[i], cnt) : 0;
        lh[i] = 0;
    }
    __syncthreads();
#pragma unroll
    for (int q = 0; q < 4; ++q) {
        if (dv[q].x < 0) continue;
        int ss[4] = {sv[q].x, sv[q].y, sv[q].z, sv[q].w};
        int dd[4] = {dv[q].x, dv[q].y, dv[q].z, dv[q].w};
#pragma unroll
        for (int j = 0; j < 4; ++j) {
            int b = dd[j] >> 5;
            int off = atomicAdd(&lh[b], 1);
            ebuf[base[b] + off] = ss[j] | ((dd[j] & 31) << 17);
        }
    }
}

// -------- fused LDS counting-sort + gather: one block (512 thr) per bucket ----------
__global__ __launch_bounds__(512) void gat_gather(
    const short* __restrict__ hb, const float* __restrict__ el,
    const float* __restrict__ er, const int* __restrict__ ebuf,
    const int* __restrict__ bcnt, const int* __restrict__ boff,
    float* __restrict__ out, int ndst)
{
    __shared__ int stage_[CAP];
    __shared__ int ssrc[CAP];
    __shared__ int lh[DPB];
    __shared__ int loff[DPB + 1];
    __shared__ int curs[DPB];

    const int b = blockIdx.x;
    const int tid = threadIdx.x;
    const int cnt = bcnt[b];
    const int gbase = boff[b];
    const int lcnt = (cnt < CAP) ? cnt : CAP;

    if (tid < DPB) lh[tid] = 0;
    __syncthreads();
    for (int i = tid; i < lcnt; i += 512) {
        int p = ebuf[gbase + i];
        stage_[i] = p;
        atomicAdd(&lh[(p >> 17) & 31], 1);
    }
    __syncthreads();
    if (tid < DPB) {
        int v = lh[tid];
#pragma unroll
        for (int o = 1; o < 32; o <<= 1) {
            int t = __shfl_up(v, o, 64);
            if (tid >= o) v += t;
        }
        loff[tid + 1] = v;
        if (tid == 0) loff[0] = 0;
    }
    __syncthreads();
    if (tid < DPB) curs[tid] = loff[tid];
    __syncthreads();
    for (int i = tid; i < lcnt; i += 512) {
        int p = stage_[i];
        int dl = (p >> 17) & 31;
        int pos = atomicAdd(&curs[dl], 1);
        ssrc[pos] = p & 0x1FFFF;
    }
    __syncthreads();

    const int wv = tid >> 6;     // 0..7
    const int l  = tid & 63;
    const int head = l >> 4;

    for (int dl = wv; dl < DPB; dl += 8) {
        int d = b * DPB + dl;
        if (d >= ndst) continue;
        int j0 = loff[dl], j1 = loff[dl + 1];
        float erv = er[d * NH + head];

        float sumA = 0.f, sumB = 0.f;
        float acc0A = 0.f, acc1A = 0.f, acc0B = 0.f, acc1B = 0.f;
        int j = j0;
        // 8-edge batches: 16 independent loads in flight before the FMA block
        for (; j + 8 <= j1; j += 8) {
            int s[8]; unsigned u[8]; float e[8];
#pragma unroll
            for (int q = 0; q < 8; ++q) s[q] = ssrc[j + q];
#pragma unroll
            for (int q = 0; q < 8; ++q)
                u[q] = *(const unsigned*)(hb + (size_t)s[q] * HD + 2 * l);
#pragma unroll
            for (int q = 0; q < 8; ++q) e[q] = el[s[q] * NH + head];
#pragma unroll
            for (int q = 0; q < 8; ++q) {
                float ev = e[q] + erv;
                ev = (ev >= 0.f) ? ev : NEG_SLOPE * ev;
                float wq = __expf(ev);
                if (q & 1) {
                    sumB += wq;
                    acc0B = fmaf(wq, bflo(u[q]), acc0B);
                    acc1B = fmaf(wq, bfhi(u[q]), acc1B);
                } else {
                    sumA += wq;
                    acc0A = fmaf(wq, bflo(u[q]), acc0A);
                    acc1A = fmaf(wq, bfhi(u[q]), acc1A);
                }
            }
        }
        for (; j + 2 <= j1; j += 2) {
            int s0 = ssrc[j], s1 = ssrc[j + 1];
            unsigned u0 = *(const unsigned*)(hb + (size_t)s0 * HD + 2 * l);
            unsigned u1 = *(const unsigned*)(hb + (size_t)s1 * HD + 2 * l);
            float e0 = el[s0 * NH + head] + erv;
            float e1 = el[s1 * NH + head] + erv;
            e0 = (e0 >= 0.f) ? e0 : NEG_SLOPE * e0;
            e1 = (e1 >= 0.f) ? e1 : NEG_SLOPE * e1;
            float w0 = __expf(e0), w1 = __expf(e1);
            sumA += w0; sumB += w1;
            acc0A = fmaf(w0, bflo(u0), acc0A); acc1A = fmaf(w0, bfhi(u0), acc1A);
            acc0B = fmaf(w1, bflo(u1), acc0B); acc1B = fmaf(w1, bfhi(u1), acc1B);
        }
        if (j < j1) {
            int s0 = ssrc[j];
            unsigned u0 = *(const unsigned*)(hb + (size_t)s0 * HD + 2 * l);
            float e0 = el[s0 * NH + head] + erv;
            e0 = (e0 >= 0.f) ? e0 : NEG_SLOPE * e0;
            float w0 = __expf(e0);
            sumA += w0;
            acc0A = fmaf(w0, bflo(u0), acc0A); acc1A = fmaf(w0, bfhi(u0), acc1A);
        }
        // overflow fallback (never taken for this input; correctness guard)
        if (cnt > CAP) {
            for (int t = CAP; t < cnt; ++t) {
                int p = ebuf[gbase + t];
                if (((p >> 17) & 31) == dl) {
                    int s0 = p & 0x1FFFF;
                    unsigned u0 = *(const unsigned*)(hb + (size_t)s0 * HD + 2 * l);
                    float e0 = el[s0 * NH + head] + erv;
                    e0 = (e0 >= 0.f) ? e0 : NEG_SLOPE * e0;
                    float w0 = __expf(e0);
                    sumA += w0;
                    acc0A = fmaf(w0, bflo(u0), acc0A); acc1A = fmaf(w0, bfhi(u0), acc1A);
                }
            }
        }
        float sum = sumA + sumB;
        bool any = (j1 > j0) || (cnt > CAP);
        float inv = any ? 1.f / sum : 0.f;
        float2 o2 = make_float2((acc0A + acc0B) * inv, (acc1A + acc1B) * inv);
        *(float2*)(out + (size_t)d * HD + 2 * l) = o2;
    }
}

// -----------------------------------------------------------------------------------
extern "C" void kernel_launch(void* const* d_in, const int* in_sizes, int n_in,
                              void* d_out, int out_size, void* d_ws, size_t ws_size,
                              hipStream_t stream)
{
    const float* x   = (const float*)d_in[0];
    const float* fw  = (const float*)d_in[1];
    const float* al  = (const float*)d_in[2];
    const float* ar  = (const float*)d_in[3];
    const int*   src = (const int*)d_in[4];
    const int*   dst = (const int*)d_in[5];
    const int*   dnid= (const int*)d_in[6];
    float* out = (float*)d_out;

    char* ws = (char*)d_ws;
    size_t off = 0;
    auto alloc = [&](size_t bytes) -> void* {
        void* p = ws + off;
        off = (off + bytes + 255) & ~(size_t)255;
        return p;
    };
    short* hb   = (short*)alloc((size_t)N_SRC_N * HD * sizeof(short));   // 25.6 MB
    short* wb   = (short*)alloc((size_t)HD * IN_F * sizeof(short));      // 64 KB
    float* el   = (float*)alloc((size_t)N_SRC_N * NH * sizeof(float));   // 1.6 MB
    float* er   = (float*)alloc((size_t)N_DST_N * NH * sizeof(float));   // 0.8 MB
    int*   ebuf = (int*)alloc((size_t)NE * sizeof(int));                 // 4 MB
    int*   bcnt = (int*)alloc((size_t)NB * sizeof(int));
    int*   boff = (int*)alloc((size_t)NB * sizeof(int));
    int*   bcur = (int*)alloc((size_t)NB * sizeof(int));

    hipMemsetAsync(bcnt, 0, (size_t)NB * sizeof(int), stream);

    cvt_w<<<(HD * IN_F / 4 + 255) / 256, 256, 0, stream>>>(fw, wb);
    gemm_fc_mfma<<<(N_SRC_N + 63) / 64, 256, 0, stream>>>(x, wb, al, hb, el, N_SRC_N);
    er_kernel<<<(N_DST_N + 3) / 4, 256, 0, stream>>>(hb, ar, dnid, er, N_DST_N);
    bucket_hist<<<(NE / 4 + 1023) / 1024, 256, 0, stream>>>((const int4*)dst, bcnt, NE / 4);
    bucket_scan<<<1, 1024, 0, stream>>>(bcnt, boff, bcur, NB);
    partition<<<(NE / 4 + 1023) / 1024, 256, 0, stream>>>((const int4*)src, (const int4*)dst,
                                                          bcur, ebuf, NE / 4);
    gat_gather<<<NB, 512, 0, stream>>>(hb, el, er, ebuf, bcnt, boff, out, N_DST_N);
}

// Round 8
// 135.258 us; speedup vs baseline: 1.0345x; 1.0345x over previous
//
#include <hip/hip_runtime.h>
#include <hip/hip_bf16.h>

#define N_SRC_N  100000
#define N_DST_N  50000
#define NE       1000000
#define IN_F     256
#define NH       4
#define ND       32
#define HD       128   // NH*ND
#define NEG_SLOPE 0.2f

#define DPB      32          // dsts per bucket
#define NB       1563        // ceil(50000/32)
#define CAP      1024        // LDS edge cap per bucket (mean 640, sd 25 -> +15 sigma)

typedef __attribute__((ext_vector_type(8))) short short8v;
typedef __attribute__((ext_vector_type(4))) short short4v;
typedef __attribute__((ext_vector_type(4))) float f32x4;

__device__ __forceinline__ short f2bf(float f) {
    __hip_bfloat16 h = __float2bfloat16(f);
    return *reinterpret_cast<short*>(&h);
}
__device__ __forceinline__ float bflo(unsigned u) { return __uint_as_float(u << 16); }
__device__ __forceinline__ float bfhi(unsigned u) { return __uint_as_float(u & 0xffff0000u); }

__device__ __forceinline__ void gl_lds16(const float* g, float* l) {
    __builtin_amdgcn_global_load_lds((const __attribute__((address_space(1))) unsigned*)g,
                                     (__attribute__((address_space(3))) unsigned*)l,
                                     16, 0, 0);
}
#define SB0() __builtin_amdgcn_sched_barrier(0)

// ---------------- convert fc_w fp32 -> bf16 -----------------------------------------
__global__ __launch_bounds__(256) void cvt_w(const float* __restrict__ w,
                                             short* __restrict__ wb)
{
    int i4 = blockIdx.x * 256 + threadIdx.x;
    if (i4 < (HD * IN_F) / 4) {
        f32x4 v = ((const f32x4*)w)[i4];
        short4v s;
        s[0] = f2bf(v[0]); s[1] = f2bf(v[1]); s[2] = f2bf(v[2]); s[3] = f2bf(v[3]);
        ((short4v*)wb)[i4] = s;
    }
}

// ---------------- persistent MFMA GEMM: hb = bf16(x @ w^T), el fused ----------------
// 625 blocks x 10 tiles of 16 rows (exactly 100000 rows). 4-buffer LDS ring, stages
// issued 3 tiles ahead, exact counted vmcnt per step (regions pinned by sched_barrier).
// Wave w owns output cols [32w,32w+32) == head w; B in 64 VGPRs, loaded once.
__global__ __launch_bounds__(256) void gemm_fc_mfma(
    const float* __restrict__ x, const short* __restrict__ wb,
    const float* __restrict__ al, short* __restrict__ hb,
    float* __restrict__ el)
{
    __shared__ float ring[4][16 * 256];   // 4 x 16KB

    const int w  = threadIdx.x >> 6;
    const int l  = threadIdx.x & 63;
    const int lr = l & 15;
    const int lk = l >> 4;
    const int row00 = blockIdx.x * 160;

    // B preload FIRST (16 vmem loads; oldest in vmcnt order)
    short8v bfr[2][8];
#pragma unroll
    for (int ct = 0; ct < 2; ++ct)
#pragma unroll
        for (int kk = 0; kk < 8; ++kk)
            bfr[ct][kk] = *(const short8v*)(wb + (size_t)(w * 32 + ct * 16 + lr) * IN_F
                                               + kk * 32 + lk * 8);
    SB0();

    // stage tile T (16 rows x 256 f32 = 16KB): 4 gl_lds per wave, rows w*4..w*4+3.
    // LDS linear dest; source pre-swizzled by ((row&7)<<4) so swizzled ds_read works.
#define STAGE(T)                                                              \
    {                                                                         \
        _Pragma("unroll")                                                     \
        for (int i = 0; i < 4; ++i) {                                         \
            int chunk = w * 4 + i;                                            \
            int srow  = row00 + (T) * 16 + chunk;                             \
            int csrc  = (l * 16) ^ ((chunk & 7) << 4);                        \
            gl_lds16(x + (size_t)srow * IN_F + (csrc >> 2),                   \
                     &ring[(T) & 3][chunk * 256]);                            \
        }                                                                     \
        SB0();                                                                \
    }

    STAGE(0) STAGE(1) STAGE(2)

    const float al0 = al[w * 32 + lr], al1 = al[w * 32 + 16 + lr];

    // one pipeline step: optionally stage T+3, wait for T's data, compute + epilogue.
#define GSTEP(T, NXT, NW)                                                     \
    {                                                                         \
        if ((NXT) >= 0) STAGE((NXT) < 0 ? 0 : (NXT))                          \
        asm volatile("s_waitcnt vmcnt(" #NW ")" ::: "memory");                \
        __builtin_amdgcn_s_barrier();                                         \
        SB0();                                                                \
        f32x4 a0 = {0.f, 0.f, 0.f, 0.f}, a1 = {0.f, 0.f, 0.f, 0.f};          \
        const char* rb = (const char*)&ring[(T) & 3][lr * 256];               \
        _Pragma("unroll")                                                     \
        for (int kk = 0; kk < 8; ++kk) {                                      \
            int b0 = (kk * 128 + lk * 32) ^ ((lr & 7) << 4);                  \
            f32x4 u0 = *(const f32x4*)(rb + b0);                              \
            f32x4 u1 = *(const f32x4*)(rb + (b0 ^ 16));                       \
            short8v af;                                                       \
            af[0] = f2bf(u0[0]); af[1] = f2bf(u0[1]);                         \
            af[2] = f2bf(u0[2]); af[3] = f2bf(u0[3]);                         \
            af[4] = f2bf(u1[0]); af[5] = f2bf(u1[1]);                         \
            af[6] = f2bf(u1[2]); af[7] = f2bf(u1[3]);                         \
            a0 = __builtin_amdgcn_mfma_f32_16x16x32_bf16(af, bfr[0][kk], a0, 0, 0, 0); \
            a1 = __builtin_amdgcn_mfma_f32_16x16x32_bf16(af, bfr[1][kk], a1, 0, 0, 0); \
        }                                                                     \
        _Pragma("unroll")                                                     \
        for (int r = 0; r < 4; ++r) {                                         \
            int row = row00 + (T) * 16 + lk * 4 + r;                          \
            short* hp = hb + (size_t)row * HD + w * 32 + lr;                  \
            hp[0]  = f2bf(a0[r]);                                             \
            hp[16] = f2bf(a1[r]);                                             \
        }                                                                     \
        float p0 = a0[0] * al0 + a1[0] * al1;                                 \
        float p1 = a0[1] * al0 + a1[1] * al1;                                 \
        float p2 = a0[2] * al0 + a1[2] * al1;                                 \
        float p3 = a0[3] * al0 + a1[3] * al1;                                 \
        _Pragma("unroll")                                                     \
        for (int o = 1; o < 16; o <<= 1) {                                    \
            p0 += __shfl_xor(p0, o, 64); p1 += __shfl_xor(p1, o, 64);         \
            p2 += __shfl_xor(p2, o, 64); p3 += __shfl_xor(p3, o, 64);         \
        }                                                                     \
        if (lr == 0) {                                                        \
            int rowe = row00 + (T) * 16 + lk * 4;                             \
            el[(rowe + 0) * NH + w] = p0;                                     \
            el[(rowe + 1) * NH + w] = p1;                                     \
            el[(rowe + 2) * NH + w] = p2;                                     \
            el[(rowe + 3) * NH + w] = p3;                                     \
        }                                                                     \
        SB0();                                                                \
        __builtin_amdgcn_s_barrier();                                         \
    }

    // vmcnt table derived from per-region vmem counts (4 loads/stage, 8-12
    // stores/step); each N forces stage T drained, keeps stages T+1..T+3 in flight.
    GSTEP(0, 3, 12)
    GSTEP(1, 4, 20)
    GSTEP(2, 5, 28)
    GSTEP(3, 6, 36)
    GSTEP(4, 7, 36)
    GSTEP(5, 8, 36)
    GSTEP(6, 9, 36)
    GSTEP(7, -1, 28)
    GSTEP(8, -1, 28)
    GSTEP(9, -1, 24)
#undef GSTEP
#undef STAGE
}

// ---------------- er[i,head] = <hb[dnid[i]], ar> per head; wave per i ---------------
__global__ __launch_bounds__(256) void er_kernel(
    const short* __restrict__ hb, const float* __restrict__ ar,
    const int* __restrict__ dnid, float* __restrict__ er, int ndst)
{
    int i = blockIdx.x * 4 + (threadIdx.x >> 6);
    if (i >= ndst) return;
    int l = threadIdx.x & 63;
    int n = dnid[i];
    unsigned u = *(const unsigned*)(hb + (size_t)n * HD + 2 * l);
    float s = bflo(u) * ar[2 * l] + bfhi(u) * ar[2 * l + 1];
#pragma unroll
    for (int o = 1; o < 16; o <<= 1) s += __shfl_xor(s, o, 64);
    if ((l & 15) == 0) er[i * NH + (l >> 4)] = s;
}

// -------- bucket histogram over dst>>5 ----------------------------------------------
__global__ __launch_bounds__(256) void bucket_hist(
    const int4* __restrict__ dst4, int* __restrict__ bcnt, int n4)
{
    __shared__ int lh[NB];
    for (int i = threadIdx.x; i < NB; i += 256) lh[i] = 0;
    __syncthreads();
#pragma unroll
    for (int q = 0; q < 4; ++q) {
        int e4 = blockIdx.x * 1024 + q * 256 + threadIdx.x;
        if (e4 < n4) {
            int4 v = dst4[e4];
            atomicAdd(&lh[v.x >> 5], 1); atomicAdd(&lh[v.y >> 5], 1);
            atomicAdd(&lh[v.z >> 5], 1); atomicAdd(&lh[v.w >> 5], 1);
        }
    }
    __syncthreads();
    for (int i = threadIdx.x; i < NB; i += 256) {
        int c = lh[i];
        if (c > 0) atomicAdd(&bcnt[i], c);
    }
}

// -------- exclusive scan of bcnt[NB] ------------------------------------------------
__global__ __launch_bounds__(1024) void bucket_scan(
    const int* __restrict__ bcnt, int* __restrict__ boff, int* __restrict__ bcur, int n)
{
    int tid = threadIdx.x;
    int i0 = 2 * tid, i1 = 2 * tid + 1;
    int a = (i0 < n) ? bcnt[i0] : 0;
    int c = (i1 < n) ? bcnt[i1] : 0;
    int s = a + c, v = s;
#pragma unroll
    for (int o = 1; o < 64; o <<= 1) {
        int t = __shfl_up(v, o, 64);
        if ((tid & 63) >= o) v += t;
    }
    __shared__ int ws[16];
    if ((tid & 63) == 63) ws[tid >> 6] = v;
    __syncthreads();
    int add = 0;
    for (int q = 0; q < (tid >> 6); ++q) add += ws[q];
    int excl = v - s + add;
    if (i0 < n) { boff[i0] = excl;     bcur[i0] = excl; }
    if (i1 < n) { boff[i1] = excl + a; bcur[i1] = excl + a; }
}

// -------- partition edges into bucket-segmented ebuf (packed src | dstlocal<<17) ----
__global__ __launch_bounds__(256) void partition(
    const int4* __restrict__ src4, const int4* __restrict__ dst4,
    int* __restrict__ bcur, int* __restrict__ ebuf, int n4)
{
    __shared__ int lh[NB];
    __shared__ int base[NB];
    for (int i = threadIdx.x; i < NB; i += 256) lh[i] = 0;
    __syncthreads();
    int4 sv[4], dv[4];
#pragma unroll
    for (int q = 0; q < 4; ++q) {
        int e4 = blockIdx.x * 1024 + q * 256 + threadIdx.x;
        if (e4 < n4) {
            sv[q] = src4[e4]; dv[q] = dst4[e4];
            atomicAdd(&lh[dv[q].x >> 5], 1); atomicAdd(&lh[dv[q].y >> 5], 1);
            atomicAdd(&lh[dv[q].z >> 5], 1); atomicAdd(&lh[dv[q].w >> 5], 1);
        } else {
            dv[q].x = -1;
        }
    }
    __syncthreads();
    for (int i = threadIdx.x; i < NB; i += 256) {
        int cnt = lh[i];
        base[i] = (cnt > 0) ? atomicAdd(&bcur[i], cnt) : 0;
        lh[i] = 0;
    }
    __syncthreads();
#pragma unroll
    for (int q = 0; q < 4; ++q) {
        if (dv[q].x < 0) continue;
        int ss[4] = {sv[q].x, sv[q].y, sv[q].z, sv[q].w};
        int dd[4] = {dv[q].x, dv[q].y, dv[q].z, dv[q].w};
#pragma unroll
        for (int j = 0; j < 4; ++j) {
            int b = dd[j] >> 5;
            int off = atomicAdd(&lh[b], 1);
            ebuf[base[b] + off] = ss[j] | ((dd[j] & 31) << 17);
        }
    }
}

// -------- fused LDS counting-sort + gather: one block per bucket (R6-proven) --------
__global__ __launch_bounds__(256) void gat_gather(
    const short* __restrict__ hb, const float* __restrict__ el,
    const float* __restrict__ er, const int* __restrict__ ebuf,
    const int* __restrict__ bcnt, const int* __restrict__ boff,
    float* __restrict__ out, int ndst)
{
    __shared__ int stage_[CAP];
    __shared__ int ssrc[CAP];
    __shared__ int lh[DPB];
    __shared__ int loff[DPB + 1];
    __shared__ int curs[DPB];

    const int b = blockIdx.x;
    const int tid = threadIdx.x;
    const int cnt = bcnt[b];
    const int gbase = boff[b];
    const int lcnt = (cnt < CAP) ? cnt : CAP;

    if (tid < DPB) lh[tid] = 0;
    __syncthreads();
    for (int i = tid; i < lcnt; i += 256) {
        int p = ebuf[gbase + i];
        stage_[i] = p;
        atomicAdd(&lh[(p >> 17) & 31], 1);
    }
    __syncthreads();
    if (tid < DPB) {
        int v = lh[tid];
#pragma unroll
        for (int o = 1; o < 32; o <<= 1) {
            int t = __shfl_up(v, o, 64);
            if (tid >= o) v += t;
        }
        loff[tid + 1] = v;
        if (tid == 0) loff[0] = 0;
    }
    __syncthreads();
    if (tid < DPB) curs[tid] = loff[tid];
    __syncthreads();
    for (int i = tid; i < lcnt; i += 256) {
        int p = stage_[i];
        int dl = (p >> 17) & 31;
        int pos = atomicAdd(&curs[dl], 1);
        ssrc[pos] = p & 0x1FFFF;
    }
    __syncthreads();

    const int wv = tid >> 6;
    const int l  = tid & 63;
    const int head = l >> 4;

    for (int dl = wv; dl < DPB; dl += 4) {
        int d = b * DPB + dl;
        if (d >= ndst) continue;
        int j0 = loff[dl], j1 = loff[dl + 1];
        float erv = er[d * NH + head];

        float sumA = 0.f, sumB = 0.f;
        float acc0A = 0.f, acc1A = 0.f, acc0B = 0.f, acc1B = 0.f;
        int j = j0;
        for (; j + 2 <= j1; j += 2) {
            int s0 = ssrc[j], s1 = ssrc[j + 1];
            unsigned u0 = *(const unsigned*)(hb + (size_t)s0 * HD + 2 * l);
            unsigned u1 = *(const unsigned*)(hb + (size_t)s1 * HD + 2 * l);
            float e0 = el[s0 * NH + head] + erv;
            float e1 = el[s1 * NH + head] + erv;
            e0 = (e0 >= 0.f) ? e0 : NEG_SLOPE * e0;
            e1 = (e1 >= 0.f) ? e1 : NEG_SLOPE * e1;
            float w0 = __expf(e0), w1 = __expf(e1);
            sumA += w0; sumB += w1;
            acc0A = fmaf(w0, bflo(u0), acc0A); acc1A = fmaf(w0, bfhi(u0), acc1A);
            acc0B = fmaf(w1, bflo(u1), acc0B); acc1B = fmaf(w1, bfhi(u1), acc1B);
        }
        if (j < j1) {
            int s0 = ssrc[j];
            unsigned u0 = *(const unsigned*)(hb + (size_t)s0 * HD + 2 * l);
            float e0 = el[s0 * NH + head] + erv;
            e0 = (e0 >= 0.f) ? e0 : NEG_SLOPE * e0;
            float w0 = __expf(e0);
            sumA += w0;
            acc0A = fmaf(w0, bflo(u0), acc0A); acc1A = fmaf(w0, bfhi(u0), acc1A);
        }
        if (cnt > CAP) {
            for (int t = CAP; t < cnt; ++t) {
                int p = ebuf[gbase + t];
                if (((p >> 17) & 31) == dl) {
                    int s0 = p & 0x1FFFF;
                    unsigned u0 = *(const unsigned*)(hb + (size_t)s0 * HD + 2 * l);
                    float e0 = el[s0 * NH + head] + erv;
                    e0 = (e0 >= 0.f) ? e0 : NEG_SLOPE * e0;
                    float w0 = __expf(e0);
                    sumA += w0;
                    acc0A = fmaf(w0, bflo(u0), acc0A); acc1A = fmaf(w0, bfhi(u0), acc1A);
                }
            }
        }
        float sum = sumA + sumB;
        bool any = (j1 > j0) || (cnt > CAP);
        float inv = any ? 1.f / sum : 0.f;
        float2 o2 = make_float2((acc0A + acc0B) * inv, (acc1A + acc1B) * inv);
        *(float2*)(out + (size_t)d * HD + 2 * l) = o2;
    }
}

// -----------------------------------------------------------------------------------
extern "C" void kernel_launch(void* const* d_in, const int* in_sizes, int n_in,
                              void* d_out, int out_size, void* d_ws, size_t ws_size,
                              hipStream_t stream)
{
    const float* x   = (const float*)d_in[0];
    const float* fw  = (const float*)d_in[1];
    const float* al  = (const float*)d_in[2];
    const float* ar  = (const float*)d_in[3];
    const int*   src = (const int*)d_in[4];
    const int*   dst = (const int*)d_in[5];
    const int*   dnid= (const int*)d_in[6];
    float* out = (float*)d_out;

    char* ws = (char*)d_ws;
    size_t off = 0;
    auto alloc = [&](size_t bytes) -> void* {
        void* p = ws + off;
        off = (off + bytes + 255) & ~(size_t)255;
        return p;
    };
    short* hb   = (short*)alloc((size_t)N_SRC_N * HD * sizeof(short));   // 25.6 MB
    short* wb   = (short*)alloc((size_t)HD * IN_F * sizeof(short));      // 64 KB
    float* el   = (float*)alloc((size_t)N_SRC_N * NH * sizeof(float));   // 1.6 MB
    float* er   = (float*)alloc((size_t)N_DST_N * NH * sizeof(float));   // 0.8 MB
    int*   ebuf = (int*)alloc((size_t)NE * sizeof(int));                 // 4 MB
    int*   bcnt = (int*)alloc((size_t)NB * sizeof(int));
    int*   boff = (int*)alloc((size_t)NB * sizeof(int));
    int*   bcur = (int*)alloc((size_t)NB * sizeof(int));

    hipMemsetAsync(bcnt, 0, (size_t)NB * sizeof(int), stream);

    cvt_w<<<(HD * IN_F / 4 + 255) / 256, 256, 0, stream>>>(fw, wb);
    gemm_fc_mfma<<<625, 256, 0, stream>>>(x, wb, al, hb, el);
    er_kernel<<<(N_DST_N + 3) / 4, 256, 0, stream>>>(hb, ar, dnid, er, N_DST_N);
    bucket_hist<<<(NE / 4 + 1023) / 1024, 256, 0, stream>>>((const int4*)dst, bcnt, NE / 4);
    bucket_scan<<<1, 1024, 0, stream>>>(bcnt, boff, bcur, NB);
    partition<<<(NE / 4 + 1023) / 1024, 256, 0, stream>>>((const int4*)src, (const int4*)dst,
                                                          bcur, ebuf, NE / 4);
    gat_gather<<<NB, 256, 0, stream>>>(hb, el, er, ebuf, bcnt, boff, out, N_DST_N);
}